// Round 3
// baseline (324.208 us; speedup 1.0000x reference)
//
#include <hip/hip_runtime.h>
#include <math.h>

#define WAVE 64
#define KMAX 32   // per-node edge-bucket capacity; P(deg>=32 | Poisson(4)) ~ 1e-18

typedef __attribute__((ext_vector_type(8))) short bf16x8;
typedef __attribute__((ext_vector_type(4))) float f32x4;

// bf16 <-> f32 helpers (bit-level, RNE on pack)
__device__ __forceinline__ unsigned short f2b(float f) {
    unsigned u = __float_as_uint(f);
    unsigned r = (u + 0x7FFFu + ((u >> 16) & 1u)) >> 16;
    return (unsigned short)r;
}
__device__ __forceinline__ float b2f(unsigned short u) {
    return __uint_as_float(((unsigned)u) << 16);
}
__device__ __forceinline__ float frcp(float x)   { return __builtin_amdgcn_rcpf(x); }
__device__ __forceinline__ float frsq(float x)   { return __builtin_amdgcn_rsqf(x); }
__device__ __forceinline__ float fsqrt2(float x) { return __builtin_amdgcn_sqrtf(x); }
__device__ __forceinline__ float silu(float x)   { return x * frcp(1.f + __expf(-x)); }
__device__ __forceinline__ float facosh(float x) { return __logf(x + fsqrt2(x * x - 1.f)); }

// ---------------------------------------------------------------------------
// Dual GEMM tail for ONE 16-node tile staged in LDS (sm[16*136], bf16 rows).
// 256-thread (4-wave) variant, used by k_main only.
// ---------------------------------------------------------------------------
__device__ __forceinline__ void dual_gemm_16(
    unsigned short* sm,
    const unsigned short* __restrict__ LW, const unsigned short* __restrict__ WT,
    const float* __restrict__ bias,
    unsigned short* __restrict__ xlin, unsigned short* __restrict__ acat,
    int base, int N, int tid)
{
    int wave = tid >> 6;
    int lane = tid & 63;
    int quad = lane >> 4;
    int l16  = lane & 15;
    int nloc = tid >> 4;

    __syncthreads();                       // sm rows fully staged by callers

    bf16x8 a[4];
    #pragma unroll
    for (int kk = 0; kk < 4; ++kk)
        a[kk] = *(const bf16x8*)&sm[l16 * 136 + kk * 32 + quad * 8];

    // GEMM 1: x @ lin_w.T  (wave handles col tiles wave*2, wave*2+1)
    f32x4 acc[2];
    acc[0] = (f32x4){0.f, 0.f, 0.f, 0.f};
    acc[1] = (f32x4){0.f, 0.f, 0.f, 0.f};
    #pragma unroll
    for (int kk = 0; kk < 4; ++kk) {
        #pragma unroll
        for (int t = 0; t < 2; ++t) {
            int nt = wave * 2 + t;
            bf16x8 b = *(const bf16x8*)&LW[(size_t)(nt * 16 + l16) * 128 + kk * 32 + quad * 8];
            acc[t] = __builtin_amdgcn_mfma_f32_16x16x32_bf16(a[kk], b, acc[t], 0, 0, 0);
        }
    }
    __syncthreads();                       // everyone done reading sm input
    #pragma unroll
    for (int t = 0; t < 2; ++t) {
        int nt = wave * 2 + t;
        float bv = bias[nt * 16 + l16];
        #pragma unroll
        for (int r = 0; r < 4; ++r)
            sm[(quad * 4 + r) * 136 + nt * 16 + l16] = f2b(acc[t][r] + bv);
    }
    __syncthreads();                       // GEMM1 result staged

    // xlin global store (coalesced bf16x8) + GEMM2 A-frags
    bf16x8 a2[4];
    #pragma unroll
    for (int kk = 0; kk < 4; ++kk)
        a2[kk] = *(const bf16x8*)&sm[l16 * 136 + kk * 32 + quad * 8];
    int node = base + nloc;
    if (node < N)
        *(bf16x8*)&xlin[(size_t)node * 128 + 8 * l16] =
            *(const bf16x8*)&sm[nloc * 136 + 8 * l16];

    // GEMM 2: xlin @ W1t
    f32x4 acc2[2];
    acc2[0] = (f32x4){0.f, 0.f, 0.f, 0.f};
    acc2[1] = (f32x4){0.f, 0.f, 0.f, 0.f};
    #pragma unroll
    for (int kk = 0; kk < 4; ++kk) {
        #pragma unroll
        for (int t = 0; t < 2; ++t) {
            int nt = wave * 2 + t;
            bf16x8 b = *(const bf16x8*)&WT[(size_t)(nt * 16 + l16) * 128 + kk * 32 + quad * 8];
            acc2[t] = __builtin_amdgcn_mfma_f32_16x16x32_bf16(a2[kk], b, acc2[t], 0, 0, 0);
        }
    }
    #pragma unroll
    for (int t = 0; t < 2; ++t) {
        int nt = wave * 2 + t;
        #pragma unroll
        for (int r = 0; r < 4; ++r) {
            int rr = base + quad * 4 + r;
            if (rr < N) acat[(size_t)rr * 128 + nt * 16 + l16] = f2b(acc2[t][r]);
        }
    }
}

// ---------------------------------------------------------------------------
// D1: weight prep (bf16 conversion + packed W1t + ae precompute) || deg zero.
// ---------------------------------------------------------------------------
__global__ __launch_bounds__(256) void k_pre(
    const float* __restrict__ lin_w, const float* __restrict__ w1,
    const float* __restrict__ b1, const float* __restrict__ emb,
    unsigned short* __restrict__ lw_bf, unsigned short* __restrict__ Wt_bf,
    float* __restrict__ ae, int* __restrict__ deg, int N, int PB)
{
    int bid = blockIdx.x, tid = threadIdx.x;
    if (bid < PB) {
        int l = bid / 129, bx = bid % 129;
        const float* lwl = lin_w + (size_t)l * 16384;
        const float* w1l = w1 + (size_t)l * 384 * 64;
        if (bx < 64) {
            int idx = bx * 256 + tid;
            lw_bf[l * 16384 + idx] = f2b(lwl[idx]);
        } else if (bx < 128) {
            int idx = (bx - 64) * 256 + tid;
            int o = idx >> 7, i = idx & 127;
            float v = (o < 64) ? w1l[i * 64 + o] : w1l[(128 + i) * 64 + (o - 64)];
            Wt_bf[l * 16384 + idx] = f2b(v);
        } else {
            int t = tid >> 6, h = tid & 63;
            float s = b1[l * 64 + h];
            #pragma unroll 8
            for (int i = 0; i < 128; ++i)
                s += emb[l * 512 + t * 128 + i] * w1l[(256 + i) * 64 + h];
            ae[l * 256 + tid] = s;
        }
    } else {
        int i0 = ((bid - PB) * 256 + tid) * 4;
        if (i0 + 3 < N) {
            *(int4*)&deg[i0] = make_int4(0, 0, 0, 0);
        } else {
            #pragma unroll
            for (int k2 = 0; k2 < 4; ++k2)
                if (i0 + k2 < N) deg[i0 + k2] = 0;
        }
    }
}

// ---------------------------------------------------------------------------
// D2: hist+scatter (edge buckets) || logmap + fused layer-0 dual GEMM.
// ---------------------------------------------------------------------------
__global__ __launch_bounds__(256) void k_main(
    const int* __restrict__ ei, const int* __restrict__ et,
    const float* __restrict__ ew, const float* __restrict__ xh,
    const float* __restrict__ curv,
    const unsigned short* __restrict__ LW, const unsigned short* __restrict__ WT,
    const float* __restrict__ lb,
    int* __restrict__ deg, int2* __restrict__ epack,
    unsigned short* __restrict__ xtan_bf,
    unsigned short* __restrict__ xlin, unsigned short* __restrict__ acat,
    int E, int N, int ECH)
{
    __shared__ __align__(16) unsigned short sm[16 * 136];
    int bid = blockIdx.x, tid = threadIdx.x;
    if (bid < ECH) {
        int e = bid * 256 + tid;
        if (e < E) {
            int dst = ei[E + e];
            int rank = atomicAdd(&deg[dst], 1);
            if (rank < KMAX) {
                int2 r;
                r.x = ei[e] | (et[e] << 24);
                r.y = __float_as_int(ew[e]);
                epack[(size_t)dst * KMAX + rank] = r;
            }
        }
        return;
    }
    // logmap (layer-0 curvature), 16 lanes per node
    int base = (bid - ECH) * 16;
    int l16  = tid & 15;
    int nloc = tid >> 4;
    int node = base + nloc;
    int nodec = node < N ? node : N - 1;

    float c = fminf(fmaxf(curv[0], 0.1f), 10.f);
    float sqc = fsqrt2(c);
    const float* row = xh + (size_t)nodec * 129;
    float x0 = row[0];
    float v[8];
    #pragma unroll
    for (int j = 0; j < 8; ++j) v[j] = row[1 + 8 * l16 + j];
    float n2 = 0.f;
    #pragma unroll
    for (int j = 0; j < 8; ++j) n2 += v[j] * v[j];
    #pragma unroll
    for (int m = 1; m < 16; m <<= 1) n2 += __shfl_xor(n2, m, WAVE);
    float nrm = fmaxf(fsqrt2(n2), 1e-6f);
    float x0c = fmaxf(sqc * x0, 1.f + 1e-7f);
    float f = facosh(x0c) * frcp(sqc) * frcp(nrm);

    bf16x8 o8;
    #pragma unroll
    for (int j = 0; j < 8; ++j) o8[j] = (short)f2b(v[j] * f);
    if (node < N)
        *(bf16x8*)&xtan_bf[(size_t)node * 128 + 8 * l16] = o8;
    *(bf16x8*)&sm[nloc * 136 + 8 * l16] = o8;

    dual_gemm_16(sm, LW, WT, lb, xlin, acat, base, N, tid);
}

// ---------------------------------------------------------------------------
// k_B: one NODE per wave, 4 edges per iteration (quad q handles edge j*4+q,
// 16 lanes x 4 H-dims per edge).  16 waves = 16 nodes per 1024-thread block.
//  - serial trip count per wave: ceil(deg/4)  (was max-of-4 deg ~ 7)
//  - every gather instruction fetches 4 edges' rows (4x lines in flight)
//  - cross-quad reduction once per node, not per edge
// Tail: dual GEMM for the next layer; GEMM1 on waves 0-7, GEMM2 on waves 8-15.
// ---------------------------------------------------------------------------
__global__ __launch_bounds__(1024, 8) void k_B(
    const int* __restrict__ deg, const int2* __restrict__ epack,
    const unsigned short* __restrict__ acat, const unsigned short* __restrict__ xlin,
    unsigned short* __restrict__ xtan_bf, const float* __restrict__ ae,
    const float* __restrict__ emb, const float* __restrict__ w2,
    const float* __restrict__ b2, const float* __restrict__ sib,
    const float* __restrict__ g, const float* __restrict__ b,
    const float* __restrict__ curv, const float* __restrict__ curv_n,
    int last, float* __restrict__ out, int N,
    const unsigned short* __restrict__ LWn, const unsigned short* __restrict__ WTn,
    const float* __restrict__ lbn,
    unsigned short* __restrict__ xlin_o, unsigned short* __restrict__ acat_o)
{
    __shared__ __align__(16) unsigned short sm[16 * 136];
    int tid  = threadIdx.x;
    int wv   = tid >> 6;                 // wave id = local node id (0..15)
    int lane = tid & 63;
    int quad = lane >> 4;
    int l16  = lane & 15;
    int base = blockIdx.x * 16;
    int wid  = base + wv;
    bool nv  = wid < N;
    int widc = nv ? wid : N - 1;

    // long-latency independent loads first
    int dg = deg[widc];
    int2 my2 = epack[(size_t)widc * KMAX + (lane & 31)];   // whole bucket in-wave
    bf16x8 xtu = *(const bf16x8*)&xtan_bf[(size_t)widc * 128 + 8 * l16];
    ushort4 adu = *(const ushort4*)&acat[(size_t)widc * 128 + 4 * l16];
    float4 w2v = *(const float4*)&w2[4 * l16];

    float c = fminf(fmaxf(curv[0], 0.1f), 10.f);
    float sqc = fsqrt2(c);
    float rsqc = frcp(sqc);
    dg = dg < KMAX ? dg : KMAX;
    dg = nv ? dg : 0;
    int jmax = (dg + 3) >> 2;            // wave-uniform (one node per wave)

    float ad0 = b2f(adu.x), ad1 = b2f(adu.y), ad2 = b2f(adu.z), ad3 = b2f(adu.w);
    float b2v = b2[0], sibv = sib[0];

    float acc[8];
    #pragma unroll
    for (int j = 0; j < 8; ++j) acc[j] = 0.f;
    float S = 0.f;
    float4 St = make_float4(0.f, 0.f, 0.f, 0.f);   // per-edge-type coeff sums

    // lookahead state (edge j*4+quad)
    ushort4 asu_n; bf16x8 xu_n; float4 av_n;
    float w_n = 1.f; int t_n = 0; bool ev_n = false;

#define FETCH(J) {                                                          \
        int eidx = (J) * 4 + quad;                                          \
        int rx = __shfl(my2.x, eidx, WAVE);                                 \
        int ry = __shfl(my2.y, eidx, WAVE);                                 \
        ev_n = eidx < dg;                                                   \
        int src = ev_n ? (rx & 0xFFFFFF) : 0;                               \
        t_n = ev_n ? (int)(((unsigned)rx) >> 24) : 0;                       \
        float wv_ = __int_as_float(ry);                                     \
        w_n = ev_n ? wv_ : 1.f;                                             \
        asu_n = *(const ushort4*)&acat[(size_t)src * 128 + 64 + 4 * l16];   \
        av_n  = *(const float4*)&ae[t_n * 64 + 4 * l16];                    \
        xu_n  = *(const bf16x8*)&xlin[(size_t)src * 128 + 8 * l16];         \
    }

    if (jmax > 0) FETCH(0);
    for (int j = 0; j < jmax; ++j) {
        ushort4 asu = asu_n; bf16x8 xu = xu_n; float4 av = av_n;
        float w = w_n; int t = t_n; bool ev = ev_n;
        if (j + 1 < jmax) FETCH(j + 1);

        // score for this quad's edge (16 lanes x 4 H-dims)
        float d = silu(ad0 + b2f(asu.x) + av.x) * w2v.x
                + silu(ad1 + b2f(asu.y) + av.y) * w2v.y
                + silu(ad2 + b2f(asu.z) + av.z) * w2v.z
                + silu(ad3 + b2f(asu.w) + av.w) * w2v.w;
        #pragma unroll
        for (int m = 1; m < 16; m <<= 1) d += __shfl_xor(d, m, WAVE);
        float s = d + b2v + __logf(fmaxf(w, 1e-6f));
        if (t == 1) s += sibv;
        float exv = ev ? __expf(s) : 0.f;
        S += exv;
        float cf = exv * w;

        // gather this quad's edge (8 dims/lane); emb handled post-loop via St
        #pragma unroll
        for (int k = 0; k < 8; ++k)
            acc[k] += b2f((unsigned short)xu[k]) * cf;
        St.x += (t == 0) ? cf : 0.f;
        St.y += (t == 1) ? cf : 0.f;
        St.z += (t == 2) ? cf : 0.f;
        St.w += (t == 3) ? cf : 0.f;
    }
#undef FETCH

    // cross-quad reduction (once per node)
    #pragma unroll
    for (int k = 0; k < 8; ++k) {
        acc[k] += __shfl_xor(acc[k], 16, WAVE);
        acc[k] += __shfl_xor(acc[k], 32, WAVE);
    }
    S += __shfl_xor(S, 16, WAVE);  S += __shfl_xor(S, 32, WAVE);
    St.x += __shfl_xor(St.x, 16, WAVE); St.x += __shfl_xor(St.x, 32, WAVE);
    St.y += __shfl_xor(St.y, 16, WAVE); St.y += __shfl_xor(St.y, 32, WAVE);
    St.z += __shfl_xor(St.z, 16, WAVE); St.z += __shfl_xor(St.z, 32, WAVE);
    St.w += __shfl_xor(St.w, 16, WAVE); St.w += __shfl_xor(St.w, 32, WAVE);

    // add emb contribution: acc += sum_t St[t] * emb[t][dims]
    #pragma unroll
    for (int tt = 0; tt < 4; ++tt) {
        float stv = (tt == 0) ? St.x : (tt == 1) ? St.y : (tt == 2) ? St.z : St.w;
        float4 em0 = *(const float4*)&emb[tt * 128 + 8 * l16];
        float4 em1 = *(const float4*)&emb[tt * 128 + 8 * l16 + 4];
        acc[0] += em0.x * stv; acc[1] += em0.y * stv;
        acc[2] += em0.z * stv; acc[3] += em0.w * stv;
        acc[4] += em1.x * stv; acc[5] += em1.y * stv;
        acc[6] += em1.z * stv; acc[7] += em1.w * stv;
    }

    float inv = frcp(S + 1e-16f);
    float y[8];
    #pragma unroll
    for (int j = 0; j < 8; ++j)
        y[j] = b2f((unsigned short)xtu[j]) + acc[j] * inv;

    // LayerNorm (16-lane reduce; all quads hold identical values)
    float sum = 0.f, sq = 0.f;
    #pragma unroll
    for (int j = 0; j < 8; ++j) { sum += y[j]; sq += y[j] * y[j]; }
    #pragma unroll
    for (int m = 1; m < 16; m <<= 1) {
        sum += __shfl_xor(sum, m, WAVE);
        sq  += __shfl_xor(sq, m, WAVE);
    }
    float mu = sum * (1.f / 128.f);
    float var = sq * (1.f / 128.f) - mu * mu;
    float invs = frsq(var + 1e-5f);
    float4 g0 = *(const float4*)&g[8 * l16];
    float4 g1 = *(const float4*)&g[8 * l16 + 4];
    float4 bb0 = *(const float4*)&b[8 * l16];
    float4 bb1 = *(const float4*)&b[8 * l16 + 4];
    y[0] = (y[0] - mu) * invs * g0.x + bb0.x;
    y[1] = (y[1] - mu) * invs * g0.y + bb0.y;
    y[2] = (y[2] - mu) * invs * g0.z + bb0.z;
    y[3] = (y[3] - mu) * invs * g0.w + bb0.w;
    y[4] = (y[4] - mu) * invs * g1.x + bb1.x;
    y[5] = (y[5] - mu) * invs * g1.y + bb1.y;
    y[6] = (y[6] - mu) * invs * g1.z + bb1.z;
    y[7] = (y[7] - mu) * invs * g1.w + bb1.w;

    // exp map
    float nrm2 = 0.f;
    #pragma unroll
    for (int j = 0; j < 8; ++j) nrm2 += y[j] * y[j];
    #pragma unroll
    for (int m = 1; m < 16; m <<= 1) nrm2 += __shfl_xor(nrm2, m, WAVE);
    float nrm = fmaxf(fsqrt2(nrm2), 1e-6f);
    float th = sqc * nrm;
    float e = __expf(th);
    float einv = frcp(e);
    float ch = 0.5f * (e + einv);
    float sh = 0.5f * (e - einv);
    float sc = sh * frcp(sqc * nrm);

    if (last) {
        if (nv && quad == 0) {
            float* o = out + (size_t)wid * 129;
            if (l16 == 0) o[0] = ch * rsqc;
            #pragma unroll
            for (int j = 0; j < 8; ++j) o[1 + 8 * l16 + j] = y[j] * sc;
        }
        return;
    }

    // analytic logmap with next layer's curvature
    float x0 = ch * rsqc;
    float c2 = fminf(fmaxf(curv_n[0], 0.1f), 10.f);
    float sqc2 = fsqrt2(c2);
    float x0c = fmaxf(sqc2 * x0, 1.f + 1e-7f);
    float dist = facosh(x0c) * frcp(sqc2);
    float nsp = fmaxf(sh * rsqc, 1e-6f);
    float sf = sc * dist * frcp(nsp);
    bf16x8 o8;
    #pragma unroll
    for (int j = 0; j < 8; ++j) o8[j] = (short)f2b(y[j] * sf);
    if (quad == 0) {
        if (nv) *(bf16x8*)&xtan_bf[(size_t)wid * 128 + 8 * l16] = o8;
        *(bf16x8*)&sm[wv * 136 + 8 * l16] = o8;     // stage (clamped row ok)
    }

    // ------- next layer's dual GEMM tail (16 waves) -------
    __syncthreads();                       // sm staged
    bf16x8 a[4];
    if (wv < 8) {
        #pragma unroll
        for (int kk = 0; kk < 4; ++kk)
            a[kk] = *(const bf16x8*)&sm[l16 * 136 + kk * 32 + quad * 8];
    }
    f32x4 acc1 = (f32x4){0.f, 0.f, 0.f, 0.f};
    if (wv < 8) {
        #pragma unroll
        for (int kk = 0; kk < 4; ++kk) {
            bf16x8 bb = *(const bf16x8*)&LWn[(size_t)(wv * 16 + l16) * 128 + kk * 32 + quad * 8];
            acc1 = __builtin_amdgcn_mfma_f32_16x16x32_bf16(a[kk], bb, acc1, 0, 0, 0);
        }
    }
    __syncthreads();                       // all reads of sm input done
    if (wv < 8) {
        float bv = lbn[wv * 16 + l16];
        #pragma unroll
        for (int r = 0; r < 4; ++r)
            sm[(quad * 4 + r) * 136 + wv * 16 + l16] = f2b(acc1[r] + bv);
    }
    __syncthreads();                       // GEMM1 result staged

    if (tid < 256) {
        int node2 = base + (tid >> 4);
        if (node2 < N)
            *(bf16x8*)&xlin_o[(size_t)node2 * 128 + 8 * (tid & 15)] =
                *(const bf16x8*)&sm[(tid >> 4) * 136 + 8 * (tid & 15)];
    }
    if (wv >= 8) {
        int ct = wv - 8;
        bf16x8 a2[4];
        #pragma unroll
        for (int kk = 0; kk < 4; ++kk)
            a2[kk] = *(const bf16x8*)&sm[l16 * 136 + kk * 32 + quad * 8];
        f32x4 acc2 = (f32x4){0.f, 0.f, 0.f, 0.f};
        #pragma unroll
        for (int kk = 0; kk < 4; ++kk) {
            bf16x8 bb = *(const bf16x8*)&WTn[(size_t)(ct * 16 + l16) * 128 + kk * 32 + quad * 8];
            acc2 = __builtin_amdgcn_mfma_f32_16x16x32_bf16(a2[kk], bb, acc2, 0, 0, 0);
        }
        #pragma unroll
        for (int r = 0; r < 4; ++r) {
            int rr = base + quad * 4 + r;
            if (rr < N) acat_o[(size_t)rr * 128 + ct * 16 + l16] = f2b(acc2[r]);
        }
    }
}

// ---------------------------------------------------------------------------
extern "C" void kernel_launch(void* const* d_in, const int* in_sizes, int n_in,
                              void* d_out, int out_size, void* d_ws, size_t ws_size,
                              hipStream_t stream) {
    const float* x_hyp = (const float*)d_in[0];
    const int*   ei    = (const int*)d_in[1];
    const int*   et    = (const int*)d_in[2];
    const float* ew    = (const float*)d_in[3];
    const float* lin_w = (const float*)d_in[4];
    const float* lin_b = (const float*)d_in[5];
    const float* ln_g  = (const float*)d_in[6];
    const float* ln_b  = (const float*)d_in[7];
    const float* emb   = (const float*)d_in[8];
    const float* w1    = (const float*)d_in[9];
    const float* b1    = (const float*)d_in[10];
    const float* w2    = (const float*)d_in[11];
    const float* b2    = (const float*)d_in[12];
    const float* sib   = (const float*)d_in[13];
    const float* curv  = (const float*)d_in[14];
    float* out = (float*)d_out;

    const int N = in_sizes[0] / 129;
    const int E = in_sizes[2];
    const int L = in_sizes[4] / (128 * 128);
    const int ECH = (E + 255) / 256;
    const int NB16 = (N + 15) / 16;
    const int PB = L * 129;
    const int ZB = (N + 1023) / 1024;

    unsigned short* xtan_bf = (unsigned short*)d_ws;              // N*128
    unsigned short* xlin0 = xtan_bf + (size_t)N * 128;            // N*128
    unsigned short* acat0 = xlin0 + (size_t)N * 128;              // N*128
    unsigned short* xlin1 = acat0 + (size_t)N * 128;              // N*128
    unsigned short* acat1 = xlin1 + (size_t)N * 128;              // N*128
    int2* epack = (int2*)(acat1 + (size_t)N * 128);               // N*KMAX
    unsigned short* lw_bf = (unsigned short*)(epack + (size_t)N * KMAX);
    unsigned short* Wt_bf = lw_bf + (size_t)L * 16384;            // L*16384
    float* ae   = (float*)(Wt_bf + (size_t)L * 16384);            // L*256
    int* deg    = (int*)(ae + (size_t)L * 256);                   // N

    // D1: weight prep + deg zeroing (fused, replaces hipMemsetAsync)
    k_pre<<<PB + ZB, 256, 0, stream>>>(lin_w, w1, b1, emb,
                                       lw_bf, Wt_bf, ae, deg, N, PB);

    // D2: hist/scatter + logmap + fused layer-0 dual GEMM
    k_main<<<ECH + NB16, 256, 0, stream>>>(
        ei, et, ew, x_hyp, curv, lw_bf, Wt_bf, lin_b,
        deg, epack, xtan_bf, xlin0, acat0, E, N, ECH);

    // D3..: per-layer fused kernel (k_B + next layer's A), ping-pong buffers
    for (int l = 0; l < L; ++l) {
        int ln = (l + 1 < L) ? l + 1 : l;
        unsigned short* xin = (l & 1) ? xlin1 : xlin0;
        unsigned short* ain = (l & 1) ? acat1 : acat0;
        unsigned short* xot = (l & 1) ? xlin0 : xlin1;
        unsigned short* aot = (l & 1) ? acat0 : acat1;
        k_B<<<NB16, 1024, 0, stream>>>(
            deg, epack, ain, xin, xtan_bf,
            ae + (size_t)l * 256, emb + (size_t)l * 512,
            w2 + (size_t)l * 64, b2 + l, sib + l,
            ln_g + (size_t)l * 128, ln_b + (size_t)l * 128,
            curv + l, curv + ln,
            l == L - 1 ? 1 : 0, out, N,
            lw_bf + (size_t)ln * 16384, Wt_bf + (size_t)ln * 16384,
            lin_b + (size_t)ln * 128, xot, aot);
    }
}

// Round 4
// 286.059 us; speedup vs baseline: 1.1334x; 1.1334x over previous
//
#include <hip/hip_runtime.h>
#include <math.h>

#define WAVE 64
#define KMAX 32   // per-node edge-bucket capacity; P(deg>=32 | Poisson(4)) ~ 1e-18

typedef __attribute__((ext_vector_type(8))) short bf16x8;
typedef __attribute__((ext_vector_type(4))) float f32x4;

// bf16 <-> f32 helpers (bit-level, RNE on pack)
__device__ __forceinline__ unsigned short f2b(float f) {
    unsigned u = __float_as_uint(f);
    unsigned r = (u + 0x7FFFu + ((u >> 16) & 1u)) >> 16;
    return (unsigned short)r;
}
__device__ __forceinline__ float b2f(unsigned short u) {
    return __uint_as_float(((unsigned)u) << 16);
}
__device__ __forceinline__ float frcp(float x)   { return __builtin_amdgcn_rcpf(x); }
__device__ __forceinline__ float frsq(float x)   { return __builtin_amdgcn_rsqf(x); }
__device__ __forceinline__ float fsqrt2(float x) { return __builtin_amdgcn_sqrtf(x); }
__device__ __forceinline__ float silu(float x)   { return x * frcp(1.f + __expf(-x)); }
__device__ __forceinline__ float facosh(float x) { return __logf(x + fsqrt2(x * x - 1.f)); }

// ---------------------------------------------------------------------------
// Dual GEMM tail for ONE 16-node tile staged in LDS (sm[16*136], bf16 rows).
// 256-thread (4-wave) variant, used by k_main only.
// ---------------------------------------------------------------------------
__device__ __forceinline__ void dual_gemm_16(
    unsigned short* sm,
    const unsigned short* __restrict__ LW, const unsigned short* __restrict__ WT,
    const float* __restrict__ bias,
    unsigned short* __restrict__ xlin, unsigned short* __restrict__ acat,
    int base, int N, int tid)
{
    int wave = tid >> 6;
    int lane = tid & 63;
    int quad = lane >> 4;
    int l16  = lane & 15;
    int nloc = tid >> 4;

    __syncthreads();                       // sm rows fully staged by callers

    bf16x8 a[4];
    #pragma unroll
    for (int kk = 0; kk < 4; ++kk)
        a[kk] = *(const bf16x8*)&sm[l16 * 136 + kk * 32 + quad * 8];

    // GEMM 1: x @ lin_w.T  (wave handles col tiles wave*2, wave*2+1)
    f32x4 acc[2];
    acc[0] = (f32x4){0.f, 0.f, 0.f, 0.f};
    acc[1] = (f32x4){0.f, 0.f, 0.f, 0.f};
    #pragma unroll
    for (int kk = 0; kk < 4; ++kk) {
        #pragma unroll
        for (int t = 0; t < 2; ++t) {
            int nt = wave * 2 + t;
            bf16x8 b = *(const bf16x8*)&LW[(size_t)(nt * 16 + l16) * 128 + kk * 32 + quad * 8];
            acc[t] = __builtin_amdgcn_mfma_f32_16x16x32_bf16(a[kk], b, acc[t], 0, 0, 0);
        }
    }
    __syncthreads();                       // everyone done reading sm input
    #pragma unroll
    for (int t = 0; t < 2; ++t) {
        int nt = wave * 2 + t;
        float bv = bias[nt * 16 + l16];
        #pragma unroll
        for (int r = 0; r < 4; ++r)
            sm[(quad * 4 + r) * 136 + nt * 16 + l16] = f2b(acc[t][r] + bv);
    }
    __syncthreads();                       // GEMM1 result staged

    // xlin global store (coalesced bf16x8) + GEMM2 A-frags
    bf16x8 a2[4];
    #pragma unroll
    for (int kk = 0; kk < 4; ++kk)
        a2[kk] = *(const bf16x8*)&sm[l16 * 136 + kk * 32 + quad * 8];
    int node = base + nloc;
    if (node < N)
        *(bf16x8*)&xlin[(size_t)node * 128 + 8 * l16] =
            *(const bf16x8*)&sm[nloc * 136 + 8 * l16];

    // GEMM 2: xlin @ W1t
    f32x4 acc2[2];
    acc2[0] = (f32x4){0.f, 0.f, 0.f, 0.f};
    acc2[1] = (f32x4){0.f, 0.f, 0.f, 0.f};
    #pragma unroll
    for (int kk = 0; kk < 4; ++kk) {
        #pragma unroll
        for (int t = 0; t < 2; ++t) {
            int nt = wave * 2 + t;
            bf16x8 b = *(const bf16x8*)&WT[(size_t)(nt * 16 + l16) * 128 + kk * 32 + quad * 8];
            acc2[t] = __builtin_amdgcn_mfma_f32_16x16x32_bf16(a2[kk], b, acc2[t], 0, 0, 0);
        }
    }
    #pragma unroll
    for (int t = 0; t < 2; ++t) {
        int nt = wave * 2 + t;
        #pragma unroll
        for (int r = 0; r < 4; ++r) {
            int rr = base + quad * 4 + r;
            if (rr < N) acat[(size_t)rr * 128 + nt * 16 + l16] = f2b(acc2[t][r]);
        }
    }
}

// ---------------------------------------------------------------------------
// D1: weight prep (bf16 conversion + packed W1t + ae precompute) || deg zero.
// ---------------------------------------------------------------------------
__global__ __launch_bounds__(256) void k_pre(
    const float* __restrict__ lin_w, const float* __restrict__ w1,
    const float* __restrict__ b1, const float* __restrict__ emb,
    unsigned short* __restrict__ lw_bf, unsigned short* __restrict__ Wt_bf,
    float* __restrict__ ae, int* __restrict__ deg, int N, int PB)
{
    int bid = blockIdx.x, tid = threadIdx.x;
    if (bid < PB) {
        int l = bid / 129, bx = bid % 129;
        const float* lwl = lin_w + (size_t)l * 16384;
        const float* w1l = w1 + (size_t)l * 384 * 64;
        if (bx < 64) {
            int idx = bx * 256 + tid;
            lw_bf[l * 16384 + idx] = f2b(lwl[idx]);
        } else if (bx < 128) {
            int idx = (bx - 64) * 256 + tid;
            int o = idx >> 7, i = idx & 127;
            float v = (o < 64) ? w1l[i * 64 + o] : w1l[(128 + i) * 64 + (o - 64)];
            Wt_bf[l * 16384 + idx] = f2b(v);
        } else {
            int t = tid >> 6, h = tid & 63;
            float s = b1[l * 64 + h];
            #pragma unroll 8
            for (int i = 0; i < 128; ++i)
                s += emb[l * 512 + t * 128 + i] * w1l[(256 + i) * 64 + h];
            ae[l * 256 + tid] = s;
        }
    } else {
        int i0 = ((bid - PB) * 256 + tid) * 4;
        if (i0 + 3 < N) {
            *(int4*)&deg[i0] = make_int4(0, 0, 0, 0);
        } else {
            #pragma unroll
            for (int k2 = 0; k2 < 4; ++k2)
                if (i0 + k2 < N) deg[i0 + k2] = 0;
        }
    }
}

// ---------------------------------------------------------------------------
// D2: hist+scatter (edge buckets) || logmap + fused layer-0 dual GEMM.
// ---------------------------------------------------------------------------
__global__ __launch_bounds__(256) void k_main(
    const int* __restrict__ ei, const int* __restrict__ et,
    const float* __restrict__ ew, const float* __restrict__ xh,
    const float* __restrict__ curv,
    const unsigned short* __restrict__ LW, const unsigned short* __restrict__ WT,
    const float* __restrict__ lb,
    int* __restrict__ deg, int2* __restrict__ epack,
    unsigned short* __restrict__ xtan_bf,
    unsigned short* __restrict__ xlin, unsigned short* __restrict__ acat,
    int E, int N, int ECH)
{
    __shared__ __align__(16) unsigned short sm[16 * 136];
    int bid = blockIdx.x, tid = threadIdx.x;
    if (bid < ECH) {
        int e = bid * 256 + tid;
        if (e < E) {
            int dst = ei[E + e];
            int rank = atomicAdd(&deg[dst], 1);
            if (rank < KMAX) {
                int2 r;
                r.x = ei[e] | (et[e] << 24);
                r.y = __float_as_int(ew[e]);
                epack[(size_t)dst * KMAX + rank] = r;
            }
        }
        return;
    }
    // logmap (layer-0 curvature), 16 lanes per node
    int base = (bid - ECH) * 16;
    int l16  = tid & 15;
    int nloc = tid >> 4;
    int node = base + nloc;
    int nodec = node < N ? node : N - 1;

    float c = fminf(fmaxf(curv[0], 0.1f), 10.f);
    float sqc = fsqrt2(c);
    const float* row = xh + (size_t)nodec * 129;
    float x0 = row[0];
    float v[8];
    #pragma unroll
    for (int j = 0; j < 8; ++j) v[j] = row[1 + 8 * l16 + j];
    float n2 = 0.f;
    #pragma unroll
    for (int j = 0; j < 8; ++j) n2 += v[j] * v[j];
    #pragma unroll
    for (int m = 1; m < 16; m <<= 1) n2 += __shfl_xor(n2, m, WAVE);
    float nrm = fmaxf(fsqrt2(n2), 1e-6f);
    float x0c = fmaxf(sqc * x0, 1.f + 1e-7f);
    float f = facosh(x0c) * frcp(sqc) * frcp(nrm);

    bf16x8 o8;
    #pragma unroll
    for (int j = 0; j < 8; ++j) o8[j] = (short)f2b(v[j] * f);
    if (node < N)
        *(bf16x8*)&xtan_bf[(size_t)node * 128 + 8 * l16] = o8;
    *(bf16x8*)&sm[nloc * 136 + 8 * l16] = o8;

    dual_gemm_16(sm, LW, WT, lb, xlin, acat, base, N, tid);
}

// ---------------------------------------------------------------------------
// k_B: one NODE per wave, 4 edges per iteration (quad q handles edge j*4+q,
// 16 lanes x 4 H-dims per edge).  16 waves = 16 nodes per 1024-thread block.
//  - serial trip count per wave: ceil(deg/4)  (was max-of-4 deg ~ 7)
//  - every gather instruction fetches 4 edges' rows (4x lines in flight)
//  - cross-quad reduction once per node, not per edge
// launch_bounds (1024, 4): 128-VGPR budget.  Round 3's (1024, 8) capped at
// 64 VGPRs -> scratch spills -> 234 MB of spill writes. 1 block/CU is fine.
// Tail: dual GEMM for the next layer; GEMM1 on waves 0-7, GEMM2 on waves 8-15.
// ---------------------------------------------------------------------------
__global__ __launch_bounds__(1024, 4) void k_B(
    const int* __restrict__ deg, const int2* __restrict__ epack,
    const unsigned short* __restrict__ acat, const unsigned short* __restrict__ xlin,
    unsigned short* __restrict__ xtan_bf, const float* __restrict__ ae,
    const float* __restrict__ emb, const float* __restrict__ w2,
    const float* __restrict__ b2, const float* __restrict__ sib,
    const float* __restrict__ g, const float* __restrict__ b,
    const float* __restrict__ curv, const float* __restrict__ curv_n,
    int last, float* __restrict__ out, int N,
    const unsigned short* __restrict__ LWn, const unsigned short* __restrict__ WTn,
    const float* __restrict__ lbn,
    unsigned short* __restrict__ xlin_o, unsigned short* __restrict__ acat_o)
{
    __shared__ __align__(16) unsigned short sm[16 * 136];
    int tid  = threadIdx.x;
    int wv   = tid >> 6;                 // wave id = local node id (0..15)
    int lane = tid & 63;
    int quad = lane >> 4;
    int l16  = lane & 15;
    int base = blockIdx.x * 16;
    int wid  = base + wv;
    bool nv  = wid < N;
    int widc = nv ? wid : N - 1;

    // long-latency independent loads first
    int dg = deg[widc];
    int2 my2 = epack[(size_t)widc * KMAX + (lane & 31)];   // whole bucket in-wave
    bf16x8 xtu = *(const bf16x8*)&xtan_bf[(size_t)widc * 128 + 8 * l16];
    ushort4 adu = *(const ushort4*)&acat[(size_t)widc * 128 + 4 * l16];
    float4 w2v = *(const float4*)&w2[4 * l16];

    float c = fminf(fmaxf(curv[0], 0.1f), 10.f);
    float sqc = fsqrt2(c);
    float rsqc = frcp(sqc);
    dg = dg < KMAX ? dg : KMAX;
    dg = nv ? dg : 0;
    int jmax = (dg + 3) >> 2;            // wave-uniform (one node per wave)

    float ad0 = b2f(adu.x), ad1 = b2f(adu.y), ad2 = b2f(adu.z), ad3 = b2f(adu.w);
    float b2v = b2[0], sibv = sib[0];

    float acc[8];
    #pragma unroll
    for (int j = 0; j < 8; ++j) acc[j] = 0.f;
    float S = 0.f;
    float4 St = make_float4(0.f, 0.f, 0.f, 0.f);   // per-edge-type coeff sums

    // lookahead state (edge j*4+quad)
    ushort4 asu_n; bf16x8 xu_n; float4 av_n;
    float w_n = 1.f; int t_n = 0; bool ev_n = false;

#define FETCH(J) {                                                          \
        int eidx = (J) * 4 + quad;                                          \
        int rx = __shfl(my2.x, eidx, WAVE);                                 \
        int ry = __shfl(my2.y, eidx, WAVE);                                 \
        ev_n = eidx < dg;                                                   \
        int src = ev_n ? (rx & 0xFFFFFF) : 0;                               \
        t_n = ev_n ? (int)(((unsigned)rx) >> 24) : 0;                       \
        float wv_ = __int_as_float(ry);                                     \
        w_n = ev_n ? wv_ : 1.f;                                             \
        asu_n = *(const ushort4*)&acat[(size_t)src * 128 + 64 + 4 * l16];   \
        av_n  = *(const float4*)&ae[t_n * 64 + 4 * l16];                    \
        xu_n  = *(const bf16x8*)&xlin[(size_t)src * 128 + 8 * l16];         \
    }

    if (jmax > 0) FETCH(0);
    for (int j = 0; j < jmax; ++j) {
        ushort4 asu = asu_n; bf16x8 xu = xu_n; float4 av = av_n;
        float w = w_n; int t = t_n; bool ev = ev_n;
        if (j + 1 < jmax) FETCH(j + 1);

        // score for this quad's edge (16 lanes x 4 H-dims)
        float d = silu(ad0 + b2f(asu.x) + av.x) * w2v.x
                + silu(ad1 + b2f(asu.y) + av.y) * w2v.y
                + silu(ad2 + b2f(asu.z) + av.z) * w2v.z
                + silu(ad3 + b2f(asu.w) + av.w) * w2v.w;
        #pragma unroll
        for (int m = 1; m < 16; m <<= 1) d += __shfl_xor(d, m, WAVE);
        float s = d + b2v + __logf(fmaxf(w, 1e-6f));
        if (t == 1) s += sibv;
        float exv = ev ? __expf(s) : 0.f;
        S += exv;
        float cf = exv * w;

        // gather this quad's edge (8 dims/lane); emb handled post-loop via St
        #pragma unroll
        for (int k = 0; k < 8; ++k)
            acc[k] += b2f((unsigned short)xu[k]) * cf;
        St.x += (t == 0) ? cf : 0.f;
        St.y += (t == 1) ? cf : 0.f;
        St.z += (t == 2) ? cf : 0.f;
        St.w += (t == 3) ? cf : 0.f;
    }
#undef FETCH

    // cross-quad reduction (once per node)
    #pragma unroll
    for (int k = 0; k < 8; ++k) {
        acc[k] += __shfl_xor(acc[k], 16, WAVE);
        acc[k] += __shfl_xor(acc[k], 32, WAVE);
    }
    S += __shfl_xor(S, 16, WAVE);  S += __shfl_xor(S, 32, WAVE);
    St.x += __shfl_xor(St.x, 16, WAVE); St.x += __shfl_xor(St.x, 32, WAVE);
    St.y += __shfl_xor(St.y, 16, WAVE); St.y += __shfl_xor(St.y, 32, WAVE);
    St.z += __shfl_xor(St.z, 16, WAVE); St.z += __shfl_xor(St.z, 32, WAVE);
    St.w += __shfl_xor(St.w, 16, WAVE); St.w += __shfl_xor(St.w, 32, WAVE);

    // add emb contribution: acc += sum_t St[t] * emb[t][dims]
    #pragma unroll
    for (int tt = 0; tt < 4; ++tt) {
        float stv = (tt == 0) ? St.x : (tt == 1) ? St.y : (tt == 2) ? St.z : St.w;
        float4 em0 = *(const float4*)&emb[tt * 128 + 8 * l16];
        float4 em1 = *(const float4*)&emb[tt * 128 + 8 * l16 + 4];
        acc[0] += em0.x * stv; acc[1] += em0.y * stv;
        acc[2] += em0.z * stv; acc[3] += em0.w * stv;
        acc[4] += em1.x * stv; acc[5] += em1.y * stv;
        acc[6] += em1.z * stv; acc[7] += em1.w * stv;
    }

    float inv = frcp(S + 1e-16f);
    float y[8];
    #pragma unroll
    for (int j = 0; j < 8; ++j)
        y[j] = b2f((unsigned short)xtu[j]) + acc[j] * inv;

    // LayerNorm (16-lane reduce; all quads hold identical values)
    float sum = 0.f, sq = 0.f;
    #pragma unroll
    for (int j = 0; j < 8; ++j) { sum += y[j]; sq += y[j] * y[j]; }
    #pragma unroll
    for (int m = 1; m < 16; m <<= 1) {
        sum += __shfl_xor(sum, m, WAVE);
        sq  += __shfl_xor(sq, m, WAVE);
    }
    float mu = sum * (1.f / 128.f);
    float var = sq * (1.f / 128.f) - mu * mu;
    float invs = frsq(var + 1e-5f);
    float4 g0 = *(const float4*)&g[8 * l16];
    float4 g1 = *(const float4*)&g[8 * l16 + 4];
    float4 bb0 = *(const float4*)&b[8 * l16];
    float4 bb1 = *(const float4*)&b[8 * l16 + 4];
    y[0] = (y[0] - mu) * invs * g0.x + bb0.x;
    y[1] = (y[1] - mu) * invs * g0.y + bb0.y;
    y[2] = (y[2] - mu) * invs * g0.z + bb0.z;
    y[3] = (y[3] - mu) * invs * g0.w + bb0.w;
    y[4] = (y[4] - mu) * invs * g1.x + bb1.x;
    y[5] = (y[5] - mu) * invs * g1.y + bb1.y;
    y[6] = (y[6] - mu) * invs * g1.z + bb1.z;
    y[7] = (y[7] - mu) * invs * g1.w + bb1.w;

    // exp map
    float nrm2 = 0.f;
    #pragma unroll
    for (int j = 0; j < 8; ++j) nrm2 += y[j] * y[j];
    #pragma unroll
    for (int m = 1; m < 16; m <<= 1) nrm2 += __shfl_xor(nrm2, m, WAVE);
    float nrm = fmaxf(fsqrt2(nrm2), 1e-6f);
    float th = sqc * nrm;
    float e = __expf(th);
    float einv = frcp(e);
    float ch = 0.5f * (e + einv);
    float sh = 0.5f * (e - einv);
    float sc = sh * frcp(sqc * nrm);

    if (last) {
        if (nv && quad == 0) {
            float* o = out + (size_t)wid * 129;
            if (l16 == 0) o[0] = ch * rsqc;
            #pragma unroll
            for (int j = 0; j < 8; ++j) o[1 + 8 * l16 + j] = y[j] * sc;
        }
        return;
    }

    // analytic logmap with next layer's curvature
    float x0 = ch * rsqc;
    float c2 = fminf(fmaxf(curv_n[0], 0.1f), 10.f);
    float sqc2 = fsqrt2(c2);
    float x0c = fmaxf(sqc2 * x0, 1.f + 1e-7f);
    float dist = facosh(x0c) * frcp(sqc2);
    float nsp = fmaxf(sh * rsqc, 1e-6f);
    float sf = sc * dist * frcp(nsp);
    bf16x8 o8;
    #pragma unroll
    for (int j = 0; j < 8; ++j) o8[j] = (short)f2b(y[j] * sf);
    if (quad == 0) {
        if (nv) *(bf16x8*)&xtan_bf[(size_t)wid * 128 + 8 * l16] = o8;
        *(bf16x8*)&sm[wv * 136 + 8 * l16] = o8;     // stage (clamped row ok)
    }

    // ------- next layer's dual GEMM tail (16 waves) -------
    __syncthreads();                       // sm staged
    bf16x8 a[4];
    if (wv < 8) {
        #pragma unroll
        for (int kk = 0; kk < 4; ++kk)
            a[kk] = *(const bf16x8*)&sm[l16 * 136 + kk * 32 + quad * 8];
    }
    f32x4 acc1 = (f32x4){0.f, 0.f, 0.f, 0.f};
    if (wv < 8) {
        #pragma unroll
        for (int kk = 0; kk < 4; ++kk) {
            bf16x8 bb = *(const bf16x8*)&LWn[(size_t)(wv * 16 + l16) * 128 + kk * 32 + quad * 8];
            acc1 = __builtin_amdgcn_mfma_f32_16x16x32_bf16(a[kk], bb, acc1, 0, 0, 0);
        }
    }
    __syncthreads();                       // all reads of sm input done
    if (wv < 8) {
        float bv = lbn[wv * 16 + l16];
        #pragma unroll
        for (int r = 0; r < 4; ++r)
            sm[(quad * 4 + r) * 136 + wv * 16 + l16] = f2b(acc1[r] + bv);
    }
    __syncthreads();                       // GEMM1 result staged

    if (tid < 256) {
        int node2 = base + (tid >> 4);
        if (node2 < N)
            *(bf16x8*)&xlin_o[(size_t)node2 * 128 + 8 * (tid & 15)] =
                *(const bf16x8*)&sm[(tid >> 4) * 136 + 8 * (tid & 15)];
    }
    if (wv >= 8) {
        int ct = wv - 8;
        bf16x8 a2[4];
        #pragma unroll
        for (int kk = 0; kk < 4; ++kk)
            a2[kk] = *(const bf16x8*)&sm[l16 * 136 + kk * 32 + quad * 8];
        f32x4 acc2 = (f32x4){0.f, 0.f, 0.f, 0.f};
        #pragma unroll
        for (int kk = 0; kk < 4; ++kk) {
            bf16x8 bb = *(const bf16x8*)&WTn[(size_t)(ct * 16 + l16) * 128 + kk * 32 + quad * 8];
            acc2 = __builtin_amdgcn_mfma_f32_16x16x32_bf16(a2[kk], bb, acc2, 0, 0, 0);
        }
        #pragma unroll
        for (int r = 0; r < 4; ++r) {
            int rr = base + quad * 4 + r;
            if (rr < N) acat_o[(size_t)rr * 128 + ct * 16 + l16] = f2b(acc2[r]);
        }
    }
}

// ---------------------------------------------------------------------------
extern "C" void kernel_launch(void* const* d_in, const int* in_sizes, int n_in,
                              void* d_out, int out_size, void* d_ws, size_t ws_size,
                              hipStream_t stream) {
    const float* x_hyp = (const float*)d_in[0];
    const int*   ei    = (const int*)d_in[1];
    const int*   et    = (const int*)d_in[2];
    const float* ew    = (const float*)d_in[3];
    const float* lin_w = (const float*)d_in[4];
    const float* lin_b = (const float*)d_in[5];
    const float* ln_g  = (const float*)d_in[6];
    const float* ln_b  = (const float*)d_in[7];
    const float* emb   = (const float*)d_in[8];
    const float* w1    = (const float*)d_in[9];
    const float* b1    = (const float*)d_in[10];
    const float* w2    = (const float*)d_in[11];
    const float* b2    = (const float*)d_in[12];
    const float* sib   = (const float*)d_in[13];
    const float* curv  = (const float*)d_in[14];
    float* out = (float*)d_out;

    const int N = in_sizes[0] / 129;
    const int E = in_sizes[2];
    const int L = in_sizes[4] / (128 * 128);
    const int ECH = (E + 255) / 256;
    const int NB16 = (N + 15) / 16;
    const int PB = L * 129;
    const int ZB = (N + 1023) / 1024;

    unsigned short* xtan_bf = (unsigned short*)d_ws;              // N*128
    unsigned short* xlin0 = xtan_bf + (size_t)N * 128;            // N*128
    unsigned short* acat0 = xlin0 + (size_t)N * 128;              // N*128
    unsigned short* xlin1 = acat0 + (size_t)N * 128;              // N*128
    unsigned short* acat1 = xlin1 + (size_t)N * 128;              // N*128
    int2* epack = (int2*)(acat1 + (size_t)N * 128);               // N*KMAX
    unsigned short* lw_bf = (unsigned short*)(epack + (size_t)N * KMAX);
    unsigned short* Wt_bf = lw_bf + (size_t)L * 16384;            // L*16384
    float* ae   = (float*)(Wt_bf + (size_t)L * 16384);            // L*256
    int* deg    = (int*)(ae + (size_t)L * 256);                   // N

    // D1: weight prep + deg zeroing (fused, replaces hipMemsetAsync)
    k_pre<<<PB + ZB, 256, 0, stream>>>(lin_w, w1, b1, emb,
                                       lw_bf, Wt_bf, ae, deg, N, PB);

    // D2: hist/scatter + logmap + fused layer-0 dual GEMM
    k_main<<<ECH + NB16, 256, 0, stream>>>(
        ei, et, ew, x_hyp, curv, lw_bf, Wt_bf, lin_b,
        deg, epack, xtan_bf, xlin0, acat0, E, N, ECH);

    // D3..: per-layer fused kernel (k_B + next layer's A), ping-pong buffers
    for (int l = 0; l < L; ++l) {
        int ln = (l + 1 < L) ? l + 1 : l;
        unsigned short* xin = (l & 1) ? xlin1 : xlin0;
        unsigned short* ain = (l & 1) ? acat1 : acat0;
        unsigned short* xot = (l & 1) ? xlin0 : xlin1;
        unsigned short* aot = (l & 1) ? acat0 : acat1;
        k_B<<<NB16, 1024, 0, stream>>>(
            deg, epack, ain, xin, xtan_bf,
            ae + (size_t)l * 256, emb + (size_t)l * 512,
            w2 + (size_t)l * 64, b2 + l, sib + l,
            ln_g + (size_t)l * 128, ln_b + (size_t)l * 128,
            curv + l, curv + ln,
            l == L - 1 ? 1 : 0, out, N,
            lw_bf + (size_t)ln * 16384, Wt_bf + (size_t)ln * 16384,
            lin_b + (size_t)ln * 128, xot, aot);
    }
}

// Round 6
// 222.516 us; speedup vs baseline: 1.4570x; 1.2856x over previous
//
#include <hip/hip_runtime.h>
#include <math.h>

#define WAVE 64
#define KMAX 32   // per-node edge-bucket capacity; P(deg>=32 | Poisson(4)) ~ 1e-18

typedef __attribute__((ext_vector_type(8))) short bf16x8;
typedef __attribute__((ext_vector_type(4))) float f32x4;

// bf16 <-> f32 helpers (bit-level, RNE on pack)
__device__ __forceinline__ unsigned short f2b(float f) {
    unsigned u = __float_as_uint(f);
    unsigned r = (u + 0x7FFFu + ((u >> 16) & 1u)) >> 16;
    return (unsigned short)r;
}
__device__ __forceinline__ float b2f(unsigned short u) {
    return __uint_as_float(((unsigned)u) << 16);
}
__device__ __forceinline__ float frcp(float x)   { return __builtin_amdgcn_rcpf(x); }
__device__ __forceinline__ float frsq(float x)   { return __builtin_amdgcn_rsqf(x); }
__device__ __forceinline__ float fsqrt2(float x) { return __builtin_amdgcn_sqrtf(x); }
__device__ __forceinline__ float silu(float x)   { return x * frcp(1.f + __expf(-x)); }
__device__ __forceinline__ float facosh(float x) { return __logf(x + fsqrt2(x * x - 1.f)); }

// ---------------------------------------------------------------------------
// Dual GEMM tail for ONE 16-node tile staged in LDS (sm[16*136], bf16 rows).
// 256-thread (4-wave) variant; 4 waves split 8 column tiles (2 per wave).
// ALL 256 threads of the block must call this (3 internal barriers).
// ---------------------------------------------------------------------------
__device__ __forceinline__ void dual_gemm_16(
    unsigned short* sm,
    const unsigned short* __restrict__ LW, const unsigned short* __restrict__ WT,
    const float* __restrict__ bias,
    unsigned short* __restrict__ xlin, unsigned short* __restrict__ acat,
    int base, int N, int tid)
{
    int wave = tid >> 6;
    int lane = tid & 63;
    int quad = lane >> 4;
    int l16  = lane & 15;
    int nloc = tid >> 4;

    __syncthreads();                       // sm rows fully staged by callers

    bf16x8 a[4];
    #pragma unroll
    for (int kk = 0; kk < 4; ++kk)
        a[kk] = *(const bf16x8*)&sm[l16 * 136 + kk * 32 + quad * 8];

    // GEMM 1: x @ lin_w.T  (wave handles col tiles wave*2, wave*2+1)
    f32x4 acc[2];
    acc[0] = (f32x4){0.f, 0.f, 0.f, 0.f};
    acc[1] = (f32x4){0.f, 0.f, 0.f, 0.f};
    #pragma unroll
    for (int kk = 0; kk < 4; ++kk) {
        #pragma unroll
        for (int t = 0; t < 2; ++t) {
            int nt = wave * 2 + t;
            bf16x8 b = *(const bf16x8*)&LW[(size_t)(nt * 16 + l16) * 128 + kk * 32 + quad * 8];
            acc[t] = __builtin_amdgcn_mfma_f32_16x16x32_bf16(a[kk], b, acc[t], 0, 0, 0);
        }
    }
    __syncthreads();                       // everyone done reading sm input
    #pragma unroll
    for (int t = 0; t < 2; ++t) {
        int nt = wave * 2 + t;
        float bv = bias[nt * 16 + l16];
        #pragma unroll
        for (int r = 0; r < 4; ++r)
            sm[(quad * 4 + r) * 136 + nt * 16 + l16] = f2b(acc[t][r] + bv);
    }
    __syncthreads();                       // GEMM1 result staged

    // xlin global store (coalesced bf16x8) + GEMM2 A-frags
    bf16x8 a2[4];
    #pragma unroll
    for (int kk = 0; kk < 4; ++kk)
        a2[kk] = *(const bf16x8*)&sm[l16 * 136 + kk * 32 + quad * 8];
    int node = base + nloc;
    if (node < N)
        *(bf16x8*)&xlin[(size_t)node * 128 + 8 * l16] =
            *(const bf16x8*)&sm[nloc * 136 + 8 * l16];

    // GEMM 2: xlin @ W1t
    f32x4 acc2[2];
    acc2[0] = (f32x4){0.f, 0.f, 0.f, 0.f};
    acc2[1] = (f32x4){0.f, 0.f, 0.f, 0.f};
    #pragma unroll
    for (int kk = 0; kk < 4; ++kk) {
        #pragma unroll
        for (int t = 0; t < 2; ++t) {
            int nt = wave * 2 + t;
            bf16x8 b = *(const bf16x8*)&WT[(size_t)(nt * 16 + l16) * 128 + kk * 32 + quad * 8];
            acc2[t] = __builtin_amdgcn_mfma_f32_16x16x32_bf16(a2[kk], b, acc2[t], 0, 0, 0);
        }
    }
    #pragma unroll
    for (int t = 0; t < 2; ++t) {
        int nt = wave * 2 + t;
        #pragma unroll
        for (int r = 0; r < 4; ++r) {
            int rr = base + quad * 4 + r;
            if (rr < N) acat[(size_t)rr * 128 + nt * 16 + l16] = f2b(acc2[t][r]);
        }
    }
}

// ---------------------------------------------------------------------------
// D1: weight prep (bf16 conversion + packed W1t + ae precompute) || deg zero.
// ---------------------------------------------------------------------------
__global__ __launch_bounds__(256) void k_pre(
    const float* __restrict__ lin_w, const float* __restrict__ w1,
    const float* __restrict__ b1, const float* __restrict__ emb,
    unsigned short* __restrict__ lw_bf, unsigned short* __restrict__ Wt_bf,
    float* __restrict__ ae, int* __restrict__ deg, int N, int PB)
{
    int bid = blockIdx.x, tid = threadIdx.x;
    if (bid < PB) {
        int l = bid / 129, bx = bid % 129;
        const float* lwl = lin_w + (size_t)l * 16384;
        const float* w1l = w1 + (size_t)l * 384 * 64;
        if (bx < 64) {
            int idx = bx * 256 + tid;
            lw_bf[l * 16384 + idx] = f2b(lwl[idx]);
        } else if (bx < 128) {
            int idx = (bx - 64) * 256 + tid;
            int o = idx >> 7, i = idx & 127;
            float v = (o < 64) ? w1l[i * 64 + o] : w1l[(128 + i) * 64 + (o - 64)];
            Wt_bf[l * 16384 + idx] = f2b(v);
        } else {
            int t = tid >> 6, h = tid & 63;
            float s = b1[l * 64 + h];
            #pragma unroll 8
            for (int i = 0; i < 128; ++i)
                s += emb[l * 512 + t * 128 + i] * w1l[(256 + i) * 64 + h];
            ae[l * 256 + tid] = s;
        }
    } else {
        int i0 = ((bid - PB) * 256 + tid) * 4;
        if (i0 + 3 < N) {
            *(int4*)&deg[i0] = make_int4(0, 0, 0, 0);
        } else {
            #pragma unroll
            for (int k2 = 0; k2 < 4; ++k2)
                if (i0 + k2 < N) deg[i0 + k2] = 0;
        }
    }
}

// ---------------------------------------------------------------------------
// D2: hist+scatter (edge buckets) || logmap + fused layer-0 dual GEMM.
// Tangent vectors stored f32 (xtf) for the residual path; bf16 copy exists
// only inside LDS staging for the MFMA A-operand.
// ---------------------------------------------------------------------------
__global__ __launch_bounds__(256) void k_main(
    const int* __restrict__ ei, const int* __restrict__ et,
    const float* __restrict__ ew, const float* __restrict__ xh,
    const float* __restrict__ curv,
    const unsigned short* __restrict__ LW, const unsigned short* __restrict__ WT,
    const float* __restrict__ lb,
    int* __restrict__ deg, int2* __restrict__ epack,
    float* __restrict__ xtf,
    unsigned short* __restrict__ xlin, unsigned short* __restrict__ acat,
    int E, int N, int ECH)
{
    __shared__ __align__(16) unsigned short sm[16 * 136];
    int bid = blockIdx.x, tid = threadIdx.x;
    if (bid < ECH) {
        int e = bid * 256 + tid;
        if (e < E) {
            int dst = ei[E + e];
            int rank = atomicAdd(&deg[dst], 1);
            if (rank < KMAX) {
                int2 r;
                r.x = ei[e] | (et[e] << 24);
                r.y = __float_as_int(ew[e]);
                epack[(size_t)dst * KMAX + rank] = r;
            }
        }
        return;
    }
    // logmap (layer-0 curvature), 16 lanes per node
    int base = (bid - ECH) * 16;
    int l16  = tid & 15;
    int nloc = tid >> 4;
    int node = base + nloc;
    int nodec = node < N ? node : N - 1;

    float c = fminf(fmaxf(curv[0], 0.1f), 10.f);
    float sqc = fsqrt2(c);
    const float* row = xh + (size_t)nodec * 129;
    float x0 = row[0];
    float v[8];
    #pragma unroll
    for (int j = 0; j < 8; ++j) v[j] = row[1 + 8 * l16 + j];
    float n2 = 0.f;
    #pragma unroll
    for (int j = 0; j < 8; ++j) n2 += v[j] * v[j];
    #pragma unroll
    for (int m = 1; m < 16; m <<= 1) n2 += __shfl_xor(n2, m, WAVE);
    float nrm = fmaxf(fsqrt2(n2), 1e-6f);
    float x0c = fmaxf(sqc * x0, 1.f + 1e-7f);
    float f = facosh(x0c) * frcp(sqc) * frcp(nrm);

    float vf[8];
    bf16x8 o8;
    #pragma unroll
    for (int j = 0; j < 8; ++j) {
        vf[j] = v[j] * f;
        o8[j] = (short)f2b(vf[j]);
    }
    if (node < N) {
        *(float4*)&xtf[(size_t)node * 128 + 8 * l16]     = make_float4(vf[0], vf[1], vf[2], vf[3]);
        *(float4*)&xtf[(size_t)node * 128 + 8 * l16 + 4] = make_float4(vf[4], vf[5], vf[6], vf[7]);
    }
    *(bf16x8*)&sm[nloc * 136 + 8 * l16] = o8;

    dual_gemm_16(sm, LW, WT, lb, xlin, acat, base, N, tid);
}

// ---------------------------------------------------------------------------
// k_B: round-2 layout (4 nodes/wave, one per quad; epilogue 4-node-parallel)
// with a 2-edges-per-iteration inner loop + pair-level 1-deep lookahead.
// Per-edge score math restored EXACTLY to the rounds-0..4 formulation
// (log-based, serial A-then-B accumulation) -- round 5's exp-fold removed.
// Residual reads f32 xtf; next-layer tangent written f32 to xtf.
// Tail: fused next-layer dual GEMM (ping-pong xlin/acat buffers).
// ---------------------------------------------------------------------------
__global__ __launch_bounds__(256) void k_B(
    const int* __restrict__ deg, const int2* __restrict__ epack,
    const unsigned short* __restrict__ acat, const unsigned short* __restrict__ xlin,
    float* __restrict__ xtf, const float* __restrict__ ae,
    const float* __restrict__ emb, const float* __restrict__ w2,
    const float* __restrict__ b2, const float* __restrict__ sib,
    const float* __restrict__ g, const float* __restrict__ b,
    const float* __restrict__ curv, const float* __restrict__ curv_n,
    int last, float* __restrict__ out, int N,
    const unsigned short* __restrict__ LWn, const unsigned short* __restrict__ WTn,
    const float* __restrict__ lbn,
    unsigned short* __restrict__ xlin_o, unsigned short* __restrict__ acat_o)
{
    __shared__ __align__(16) unsigned short sm[16 * 136];
    int tid = threadIdx.x;
    int lane = tid & 63;
    int quad = lane >> 4;
    int l16  = lane & 15;
    int gw = (blockIdx.x * 256 + tid) >> 6;      // global wave id
    int wid = gw * 4 + quad;                     // node id (one per quad)
    bool nv = wid < N;
    int widc = nv ? wid : N - 1;

    // long-latency independent loads first
    int dg = deg[widc];
    const int4* bp = (const int4*)(epack + (size_t)widc * KMAX);
    int4 myent = bp[l16];                        // bucket entries 2*l16, 2*l16+1
    float4 xt0 = *(const float4*)&xtf[(size_t)widc * 128 + 8 * l16];
    float4 xt1 = *(const float4*)&xtf[(size_t)widc * 128 + 8 * l16 + 4];
    ushort4 adu = *(const ushort4*)&acat[(size_t)widc * 128 + 4 * l16];
    float4 w2v = *(const float4*)&w2[4 * l16];

    float c = fminf(fmaxf(curv[0], 0.1f), 10.f);
    float sqc = fsqrt2(c);
    float rsqc = frcp(sqc);
    dg = dg < KMAX ? dg : KMAX;
    dg = nv ? dg : 0;

    float ad0 = b2f(adu.x), ad1 = b2f(adu.y), ad2 = b2f(adu.z), ad3 = b2f(adu.w);
    float b2v = b2[0], sibv = sib[0];

    float acc[8];
    #pragma unroll
    for (int j = 0; j < 8; ++j) acc[j] = 0.f;
    float S = 0.f;
    float4 St = make_float4(0.f, 0.f, 0.f, 0.f);   // per-edge-type coeff sums

    // wave-uniform pair-trip count (max over the 4 quads)
    int jm = dg;
    jm = max(jm, __shfl_xor(jm, 16, WAVE));
    jm = max(jm, __shfl_xor(jm, 32, WAVE));
    int jmax = (jm + 1) >> 1;

    // pair lookahead state (edges 2j, 2j+1 of this quad's node)
    ushort4 asuA_n, asuB_n; bf16x8 xuA_n, xuB_n; float4 avA_n, avB_n;
    float wA_n = 1.f, wB_n = 1.f; int tA_n = 0, tB_n = 0;
    bool eA_n = false, eB_n = false;

#define FETCHP(J) {                                                           \
        int lsrc = (quad << 4) + (J);                                         \
        int r0x = __shfl(myent.x, lsrc, WAVE);                                \
        int r0y = __shfl(myent.y, lsrc, WAVE);                                \
        int r1x = __shfl(myent.z, lsrc, WAVE);                                \
        int r1y = __shfl(myent.w, lsrc, WAVE);                                \
        eA_n = (2 * (J)) < dg;                                                \
        eB_n = (2 * (J) + 1) < dg;                                            \
        int sA = eA_n ? (r0x & 0xFFFFFF) : 0;                                 \
        int sB = eB_n ? (r1x & 0xFFFFFF) : 0;                                 \
        tA_n = eA_n ? (int)(((unsigned)r0x) >> 24) : 0;                       \
        tB_n = eB_n ? (int)(((unsigned)r1x) >> 24) : 0;                       \
        wA_n = eA_n ? __int_as_float(r0y) : 1.f;                              \
        wB_n = eB_n ? __int_as_float(r1y) : 1.f;                              \
        asuA_n = *(const ushort4*)&acat[(size_t)sA * 128 + 64 + 4 * l16];     \
        asuB_n = *(const ushort4*)&acat[(size_t)sB * 128 + 64 + 4 * l16];     \
        avA_n  = *(const float4*)&ae[tA_n * 64 + 4 * l16];                    \
        avB_n  = *(const float4*)&ae[tB_n * 64 + 4 * l16];                    \
        xuA_n  = *(const bf16x8*)&xlin[(size_t)sA * 128 + 8 * l16];           \
        xuB_n  = *(const bf16x8*)&xlin[(size_t)sB * 128 + 8 * l16];           \
    }

    if (jmax > 0) FETCHP(0);
    for (int j = 0; j < jmax; ++j) {
        ushort4 asuA = asuA_n, asuB = asuB_n;
        bf16x8 xuA = xuA_n, xuB = xuB_n;
        float4 avA = avA_n, avB = avB_n;
        float wA = wA_n, wB = wB_n;
        int tA = tA_n, tB = tB_n;
        bool eA = eA_n, eB = eB_n;
        if (j + 1 < jmax) FETCHP(j + 1);

        // ---- edge A (exact rounds-0..4 per-edge math) ----
        float dA = silu(ad0 + b2f(asuA.x) + avA.x) * w2v.x
                 + silu(ad1 + b2f(asuA.y) + avA.y) * w2v.y
                 + silu(ad2 + b2f(asuA.z) + avA.z) * w2v.z
                 + silu(ad3 + b2f(asuA.w) + avA.w) * w2v.w;
        // ---- edge B ----
        float dB = silu(ad0 + b2f(asuB.x) + avB.x) * w2v.x
                 + silu(ad1 + b2f(asuB.y) + avB.y) * w2v.y
                 + silu(ad2 + b2f(asuB.z) + avB.z) * w2v.z
                 + silu(ad3 + b2f(asuB.w) + avB.w) * w2v.w;
        #pragma unroll
        for (int m = 1; m < 16; m <<= 1) {
            dA += __shfl_xor(dA, m, WAVE);
            dB += __shfl_xor(dB, m, WAVE);
        }
        float sA = dA + b2v + __logf(fmaxf(wA, 1e-6f));
        if (tA == 1) sA += sibv;
        float exA = eA ? __expf(sA) : 0.f;
        S += exA;
        float cfA = exA * wA;

        float sB2 = dB + b2v + __logf(fmaxf(wB, 1e-6f));
        if (tB == 1) sB2 += sibv;
        float exB = eB ? __expf(sB2) : 0.f;
        S += exB;
        float cfB = exB * wB;

        // gather both edges (8 dims/lane); emb handled post-loop via St
        #pragma unroll
        for (int k = 0; k < 8; ++k)
            acc[k] += b2f((unsigned short)xuA[k]) * cfA;
        #pragma unroll
        for (int k = 0; k < 8; ++k)
            acc[k] += b2f((unsigned short)xuB[k]) * cfB;
        St.x += (tA == 0) ? cfA : 0.f;
        St.y += (tA == 1) ? cfA : 0.f;
        St.z += (tA == 2) ? cfA : 0.f;
        St.w += (tA == 3) ? cfA : 0.f;
        St.x += (tB == 0) ? cfB : 0.f;
        St.y += (tB == 1) ? cfB : 0.f;
        St.z += (tB == 2) ? cfB : 0.f;
        St.w += (tB == 3) ? cfB : 0.f;
    }
#undef FETCHP

    // add emb contribution: acc += sum_t St[t] * emb[t][dims]
    #pragma unroll
    for (int tt = 0; tt < 4; ++tt) {
        float stv = (tt == 0) ? St.x : (tt == 1) ? St.y : (tt == 2) ? St.z : St.w;
        float4 em0 = *(const float4*)&emb[tt * 128 + 8 * l16];
        float4 em1 = *(const float4*)&emb[tt * 128 + 8 * l16 + 4];
        acc[0] += em0.x * stv; acc[1] += em0.y * stv;
        acc[2] += em0.z * stv; acc[3] += em0.w * stv;
        acc[4] += em1.x * stv; acc[5] += em1.y * stv;
        acc[6] += em1.z * stv; acc[7] += em1.w * stv;
    }

    float inv = frcp(S + 1e-16f);
    float y[8];
    y[0] = xt0.x + acc[0] * inv;
    y[1] = xt0.y + acc[1] * inv;
    y[2] = xt0.z + acc[2] * inv;
    y[3] = xt0.w + acc[3] * inv;
    y[4] = xt1.x + acc[4] * inv;
    y[5] = xt1.y + acc[5] * inv;
    y[6] = xt1.z + acc[6] * inv;
    y[7] = xt1.w + acc[7] * inv;

    // LayerNorm (16-lane reduce covers all 128 dims)
    float sum = 0.f, sq = 0.f;
    #pragma unroll
    for (int j = 0; j < 8; ++j) { sum += y[j]; sq += y[j] * y[j]; }
    #pragma unroll
    for (int m = 1; m < 16; m <<= 1) {
        sum += __shfl_xor(sum, m, WAVE);
        sq  += __shfl_xor(sq, m, WAVE);
    }
    float mu = sum * (1.f / 128.f);
    float var = sq * (1.f / 128.f) - mu * mu;
    float invs = frsq(var + 1e-5f);
    float4 g0 = *(const float4*)&g[8 * l16];
    float4 g1 = *(const float4*)&g[8 * l16 + 4];
    float4 bb0 = *(const float4*)&b[8 * l16];
    float4 bb1 = *(const float4*)&b[8 * l16 + 4];
    y[0] = (y[0] - mu) * invs * g0.x + bb0.x;
    y[1] = (y[1] - mu) * invs * g0.y + bb0.y;
    y[2] = (y[2] - mu) * invs * g0.z + bb0.z;
    y[3] = (y[3] - mu) * invs * g0.w + bb0.w;
    y[4] = (y[4] - mu) * invs * g1.x + bb1.x;
    y[5] = (y[5] - mu) * invs * g1.y + bb1.y;
    y[6] = (y[6] - mu) * invs * g1.z + bb1.z;
    y[7] = (y[7] - mu) * invs * g1.w + bb1.w;

    // exp map
    float nrm2 = 0.f;
    #pragma unroll
    for (int j = 0; j < 8; ++j) nrm2 += y[j] * y[j];
    #pragma unroll
    for (int m = 1; m < 16; m <<= 1) nrm2 += __shfl_xor(nrm2, m, WAVE);
    float nrm = fmaxf(fsqrt2(nrm2), 1e-6f);
    float th = sqc * nrm;
    float e = __expf(th);
    float einv = frcp(e);
    float ch = 0.5f * (e + einv);
    float sh = 0.5f * (e - einv);
    float sc = sh * frcp(sqc * nrm);

    if (last) {
        if (nv) {
            float* o = out + (size_t)wid * 129;
            if (l16 == 0) o[0] = ch * rsqc;
            #pragma unroll
            for (int j = 0; j < 8; ++j) o[1 + 8 * l16 + j] = y[j] * sc;
        }
    } else {
        // analytic logmap with next layer's curvature
        float x0 = ch * rsqc;
        float c2 = fminf(fmaxf(curv_n[0], 0.1f), 10.f);
        float sqc2 = fsqrt2(c2);
        float x0c = fmaxf(sqc2 * x0, 1.f + 1e-7f);
        float dist = facosh(x0c) * frcp(sqc2);
        float nsp = fmaxf(sh * rsqc, 1e-6f);
        float sf = sc * dist * frcp(nsp);
        float tf[8];
        bf16x8 o8;
        #pragma unroll
        for (int j = 0; j < 8; ++j) {
            tf[j] = y[j] * sf;
            o8[j] = (short)f2b(tf[j]);
        }
        if (nv) {
            *(float4*)&xtf[(size_t)wid * 128 + 8 * l16]     = make_float4(tf[0], tf[1], tf[2], tf[3]);
            *(float4*)&xtf[(size_t)wid * 128 + 8 * l16 + 4] = make_float4(tf[4], tf[5], tf[6], tf[7]);
        }
        // stage next-layer tangent into LDS and run next layer's dual GEMM
        *(bf16x8*)&sm[(tid >> 4) * 136 + 8 * l16] = o8;
        dual_gemm_16(sm, LWn, WTn, lbn, xlin_o, acat_o, blockIdx.x * 16, N, tid);
    }
}

// ---------------------------------------------------------------------------
extern "C" void kernel_launch(void* const* d_in, const int* in_sizes, int n_in,
                              void* d_out, int out_size, void* d_ws, size_t ws_size,
                              hipStream_t stream) {
    const float* x_hyp = (const float*)d_in[0];
    const int*   ei    = (const int*)d_in[1];
    const int*   et    = (const int*)d_in[2];
    const float* ew    = (const float*)d_in[3];
    const float* lin_w = (const float*)d_in[4];
    const float* lin_b = (const float*)d_in[5];
    const float* ln_g  = (const float*)d_in[6];
    const float* ln_b  = (const float*)d_in[7];
    const float* emb   = (const float*)d_in[8];
    const float* w1    = (const float*)d_in[9];
    const float* b1    = (const float*)d_in[10];
    const float* w2    = (const float*)d_in[11];
    const float* b2    = (const float*)d_in[12];
    const float* sib   = (const float*)d_in[13];
    const float* curv  = (const float*)d_in[14];
    float* out = (float*)d_out;

    const int N = in_sizes[0] / 129;
    const int E = in_sizes[2];
    const int L = in_sizes[4] / (128 * 128);
    const int ECH = (E + 255) / 256;
    const int NB16 = (N + 15) / 16;
    const int PB = L * 129;
    const int ZB = (N + 1023) / 1024;

    float* xtf = (float*)d_ws;                                    // N*128 f32
    unsigned short* xlin0 = (unsigned short*)(xtf + (size_t)N * 128);
    unsigned short* acat0 = xlin0 + (size_t)N * 128;              // N*128 bf16
    unsigned short* xlin1 = acat0 + (size_t)N * 128;              // N*128 bf16
    unsigned short* acat1 = xlin1 + (size_t)N * 128;              // N*128 bf16
    int2* epack = (int2*)(acat1 + (size_t)N * 128);               // N*KMAX
    unsigned short* lw_bf = (unsigned short*)(epack + (size_t)N * KMAX);
    unsigned short* Wt_bf = lw_bf + (size_t)L * 16384;            // L*16384
    float* ae   = (float*)(Wt_bf + (size_t)L * 16384);            // L*256
    int* deg    = (int*)(ae + (size_t)L * 256);                   // N

    // D1: weight prep + deg zeroing (fused, replaces hipMemsetAsync)
    k_pre<<<PB + ZB, 256, 0, stream>>>(lin_w, w1, b1, emb,
                                       lw_bf, Wt_bf, ae, deg, N, PB);

    // D2: hist/scatter + logmap + fused layer-0 dual GEMM
    k_main<<<ECH + NB16, 256, 0, stream>>>(
        ei, et, ew, x_hyp, curv, lw_bf, Wt_bf, lin_b,
        deg, epack, xtf, xlin0, acat0, E, N, ECH);

    // D3..: per-layer fused kernel (k_B + next layer's A), ping-pong buffers
    for (int l = 0; l < L; ++l) {
        int ln = (l + 1 < L) ? l + 1 : l;
        unsigned short* xin = (l & 1) ? xlin1 : xlin0;
        unsigned short* ain = (l & 1) ? acat1 : acat0;
        unsigned short* xot = (l & 1) ? xlin0 : xlin1;
        unsigned short* aot = (l & 1) ? acat0 : acat1;
        k_B<<<NB16, 256, 0, stream>>>(
            deg, epack, ain, xin, xtf,
            ae + (size_t)l * 256, emb + (size_t)l * 512,
            w2 + (size_t)l * 64, b2 + l, sib + l,
            ln_g + (size_t)l * 128, ln_b + (size_t)l * 128,
            curv + l, curv + ln,
            l == L - 1 ? 1 : 0, out, N,
            lw_bf + (size_t)ln * 16384, Wt_bf + (size_t)ln * 16384,
            lin_b + (size_t)ln * 128, xot, aot);
    }
}